// Round 7
// baseline (489.911 us; speedup 1.0000x reference)
//
#include <hip/hip_runtime.h>
#include <math.h>

#define T_STEPS 48
#define N_NODES 1000
#define E_EDGES 32000
#define DIN     32
#define H_DIM   64

// ---- workspace layout (4-byte units) ----
#define O_INDEG  0         // int[1000]
#define O_FILL   1024      // int[1000]
#define O_ROWPTR 2048      // int[1001]
#define O_CSRC   4096      // int[32000]
#define O_CNORM  36864     // f32[32000]
#define O_DINV   69632     // f32[1000]
#define O_SELF   70656     // f32[1000]
#define O_BUF0   71680                    // f32[48*64000]  T1 -> T2 -> HS
#define O_BUF1   (71680 + 3072000)        // f32[48*64000]  G1 -> G2 -> part

__device__ __forceinline__ float sigmf(float v) { return 1.0f / (1.0f + __expf(-v)); }

// global -> LDS direct (16B per lane); dest must be wave-uniform base + lane*16
__device__ __forceinline__ void gld16(const void* g, void* l) {
  __builtin_amdgcn_global_load_lds((const __attribute__((address_space(1))) void*)g,
                                   (__attribute__((address_space(3))) void*)l, 16, 0, 0);
}

// ---------------- setup ----------------
__global__ void k_zero(int* __restrict__ p) { p[blockIdx.x * 256 + threadIdx.x] = 0; }

__global__ void k_count(const int* __restrict__ ei, int* __restrict__ indeg) {
  int e = blockIdx.x * 256 + threadIdx.x;
  if (e < E_EDGES) atomicAdd(&indeg[ei[E_EDGES + e]], 1);
}

__global__ void k_scan(const int* __restrict__ indeg, int* __restrict__ rowptr,
                       float* __restrict__ dinv, float* __restrict__ selfn) {
  __shared__ int sdat[1024];
  int tid = threadIdx.x;
  int v = (tid < N_NODES) ? indeg[tid] : 0;
  sdat[tid] = v;
  __syncthreads();
  for (int off = 1; off < 1024; off <<= 1) {
    int add = (tid >= off) ? sdat[tid - off] : 0;
    __syncthreads();
    sdat[tid] += add;
    __syncthreads();
  }
  if (tid < N_NODES) {
    rowptr[tid + 1] = sdat[tid];
    float di = rsqrtf((float)(v + 1));
    dinv[tid] = di;
    selfn[tid] = di * di;
  }
  if (tid == 0) rowptr[0] = 0;
}

__global__ void k_scatter(const int* __restrict__ ei, const int* __restrict__ rowptr,
                          int* __restrict__ fill, const float* __restrict__ dinv,
                          int* __restrict__ csrc, float* __restrict__ cnorm) {
  int e = blockIdx.x * 256 + threadIdx.x;
  if (e >= E_EDGES) return;
  int s = ei[e], d = ei[E_EDGES + e];
  int pos = atomicAdd(&fill[d], 1);
  int idx = rowptr[d] + pos;
  csrc[idx] = s;
  cnorm[idx] = dinv[s] * dinv[d];
}

// ---------------- T1 = x @ Wg1 ----------------
__global__ void __launch_bounds__(256) k_t1(const float* __restrict__ x,
                                            const float* __restrict__ Wg1,
                                            float* __restrict__ T1) {
  __shared__ float sWT[H_DIM * 36];     // transposed: sWT[h][k]
  __shared__ float sx[4][DIN];
  const int tid = threadIdx.x, wv = tid >> 6, h = tid & 63;
  for (int i = tid; i < DIN * H_DIM; i += 256) sWT[(i & 63) * 36 + (i >> 6)] = Wg1[i];
  __syncthreads();
  const int r0 = blockIdx.x * 64 + wv * 16;
  const float4* wrow = (const float4*)&sWT[h * 36];
  for (int it = 0; it < 16; ++it) {
    const int r = r0 + it;
    if (h < DIN) sx[wv][h] = x[r * DIN + h];   // wave-local
    float acc = 0.f;
    const float4* xp = (const float4*)&sx[wv][0];
#pragma unroll
    for (int k4 = 0; k4 < 8; ++k4) {
      float4 xv = xp[k4], wv4 = wrow[k4];
      acc += xv.x * wv4.x + xv.y * wv4.y + xv.z * wv4.z + xv.w * wv4.w;
    }
    T1[r * H_DIM + h] = acc;
  }
}

// ---------------- gather: dst = gather(Tsrc)+self+bias, optional relu ----------------
// 8-deep rotating prefetch: batch k+1's loads issue while batch k's FMAs run.
__device__ __forceinline__ float gath_node(const float* __restrict__ Tsrc,
                                           const int* __restrict__ es,
                                           const float* __restrict__ ew,
                                           int cnt, int h) {
  float a0 = 0.f, a1 = 0.f, a2 = 0.f, a3 = 0.f;
  float a4 = 0.f, a5 = 0.f, a6 = 0.f, a7 = 0.f;
  int e = 0;
  if (cnt >= 8) {
    float p0 = Tsrc[es[0] * 64 + h], p1 = Tsrc[es[1] * 64 + h];
    float p2 = Tsrc[es[2] * 64 + h], p3 = Tsrc[es[3] * 64 + h];
    float p4 = Tsrc[es[4] * 64 + h], p5 = Tsrc[es[5] * 64 + h];
    float p6 = Tsrc[es[6] * 64 + h], p7 = Tsrc[es[7] * 64 + h];
    for (e = 8; e + 8 <= cnt; e += 8) {
      float n0 = Tsrc[es[e + 0] * 64 + h], n1 = Tsrc[es[e + 1] * 64 + h];
      float n2 = Tsrc[es[e + 2] * 64 + h], n3 = Tsrc[es[e + 3] * 64 + h];
      float n4 = Tsrc[es[e + 4] * 64 + h], n5 = Tsrc[es[e + 5] * 64 + h];
      float n6 = Tsrc[es[e + 6] * 64 + h], n7 = Tsrc[es[e + 7] * 64 + h];
      a0 += ew[e - 8] * p0; a1 += ew[e - 7] * p1;
      a2 += ew[e - 6] * p2; a3 += ew[e - 5] * p3;
      a4 += ew[e - 4] * p4; a5 += ew[e - 3] * p5;
      a6 += ew[e - 2] * p6; a7 += ew[e - 1] * p7;
      p0 = n0; p1 = n1; p2 = n2; p3 = n3; p4 = n4; p5 = n5; p6 = n6; p7 = n7;
    }
    a0 += ew[e - 8] * p0; a1 += ew[e - 7] * p1;
    a2 += ew[e - 6] * p2; a3 += ew[e - 5] * p3;
    a4 += ew[e - 4] * p4; a5 += ew[e - 3] * p5;
    a6 += ew[e - 2] * p6; a7 += ew[e - 1] * p7;
  }
  for (; e < cnt; ++e) a0 += ew[e] * Tsrc[es[e] * 64 + h];
  return ((a0 + a1) + (a2 + a3)) + ((a4 + a5) + (a6 + a7));
}

// 32 nodes / block -> 1536 blocks (6/CU) for latency-hiding TLP
#define ECHUNK 1536
__global__ void __launch_bounds__(256) k_gath(const float* __restrict__ Tall,
                                              const float* __restrict__ bias,
                                              const int* __restrict__ rowptr,
                                              const int* __restrict__ csrc,
                                              const float* __restrict__ cnorm,
                                              const float* __restrict__ selfn,
                                              float* __restrict__ Dall, int relu) {
  __shared__ int   s_src[ECHUNK];
  __shared__ float s_wt[ECHUNK];
  __shared__ float sb[64];
  const int tid = threadIdx.x, wv = tid >> 6, h = tid & 63;
  if (tid < 64) sb[tid] = bias[tid];
  const int t = blockIdx.x >> 5, nb32 = (blockIdx.x & 31) * 32;
  const float* Tsrc = Tall + t * 64000;
  float* dst = Dall + t * 64000;
  const int nE = (nb32 + 32 < N_NODES) ? nb32 + 32 : N_NODES;
  const int r0 = rowptr[nb32], r1 = rowptr[nE];
  const int tot = r1 - r0;
  const bool fits = (tot <= ECHUNK);
  if (fits)
    for (int i = tid; i < tot; i += 256) { s_src[i] = csrc[r0 + i]; s_wt[i] = cnorm[r0 + i]; }
  __syncthreads();
  for (int i = 0; i < 8; ++i) {
    const int n = nb32 + wv * 8 + i;
    if (n >= N_NODES) continue;
    const int a = rowptr[n], b = rowptr[n + 1];
    float acc = selfn[n] * Tsrc[n * 64 + h];
    if (fits) {
      acc += gath_node(Tsrc, s_src + (a - r0), s_wt + (a - r0), b - a, h);
    } else {
      for (int e = a; e < b; ++e) acc += cnorm[e] * Tsrc[csrc[e] * 64 + h];
    }
    acc += sb[h];
    if (relu) acc = fmaxf(acc, 0.f);
    dst[n * 64 + h] = acc;
  }
}

// ---------------- T2 = G1 @ Wg2 (48000 x 64 x 64) ----------------
__global__ void __launch_bounds__(256) k_mm2(const float* __restrict__ G1,
                                             const float* __restrict__ Wg2,
                                             float* __restrict__ T2) {
  __shared__ float sW[H_DIM * H_DIM];   // [k][h] broadcast form, conflict-free
  __shared__ float sx[4][H_DIM];
  const int tid = threadIdx.x, wv = tid >> 6, h = tid & 63;
  for (int i = tid; i < H_DIM * H_DIM; i += 256) sW[i] = Wg2[i];
  __syncthreads();
  const int r0 = blockIdx.x * 64 + wv * 16;
  for (int it = 0; it < 16; ++it) {
    const int r = r0 + it;
    sx[wv][h] = G1[r * 64 + h];   // wave-local write then read
    float acc = 0.f;
#pragma unroll
    for (int k = 0; k < H_DIM; ++k) acc += sx[wv][k] * sW[k * H_DIM + h];
    T2[r * 64 + h] = acc;
  }
}

// ---------------- LSTM scan: 1 node / block ----------------
__global__ void __launch_bounds__(256) k_lstm(const float* __restrict__ G2,
                                              const float* __restrict__ h0,
                                              const float* __restrict__ c0,
                                              const float* __restrict__ Wih,
                                              const float* __restrict__ Whh,
                                              const float* __restrict__ bih,
                                              const float* __restrict__ bhh,
                                              float* __restrict__ hsg,
                                              float* __restrict__ outp) {
  const int tid = threadIdx.x, nb = blockIdx.x;
  __shared__ float sh[64];
  __shared__ float sg2[2][64];
  __shared__ float sgates[256];
  float4 Wih4[16], Whh4[16];
  {
    const float4* wp = (const float4*)(Wih + tid * H_DIM);
    const float4* vp = (const float4*)(Whh + tid * H_DIM);
#pragma unroll
    for (int k = 0; k < 16; ++k) { Wih4[k] = wp[k]; Whh4[k] = vp[k]; }
  }
  const float bsum = bih[tid] + bhh[tid];
  float creg = 0.f;
  if (tid < 64) {
    sh[tid] = h0[nb * 64 + tid];
    creg = c0[nb * 64 + tid];
    sg2[0][tid] = G2[nb * 64 + tid];
  }
  __syncthreads();
  for (int t = 0; t < T_STEPS; ++t) {
    const int cur = t & 1;
    float gnext = 0.f;
    if (t < T_STEPS - 1 && tid < 64) gnext = G2[(t + 1) * 64000 + nb * 64 + tid];
    float gv = bsum;
    const float4* gp = (const float4*)&sg2[cur][0];
    const float4* hp = (const float4*)sh;
#pragma unroll
    for (int k = 0; k < 16; ++k) {
      float4 a = gp[k], b = hp[k];
      gv += a.x * Wih4[k].x + a.y * Wih4[k].y + a.z * Wih4[k].z + a.w * Wih4[k].w;
      gv += b.x * Whh4[k].x + b.y * Whh4[k].y + b.z * Whh4[k].z + b.w * Whh4[k].w;
    }
    sgates[tid] = gv;
    __syncthreads();
    if (tid < 64) {
      float iv = sgates[tid], fv = sgates[64 + tid], gg = sgates[128 + tid], ov = sgates[192 + tid];
      float cn = sigmf(fv) * creg + sigmf(iv) * tanhf(gg);
      float hn = sigmf(ov) * tanhf(cn);
      creg = cn;
      sh[tid] = hn;
      hsg[t * 64000 + nb * 64 + tid] = hn;
      if (t < T_STEPS - 1) sg2[cur ^ 1][tid] = gnext;
    }
    __syncthreads();
  }
  if (tid < 64) {
    outp[48000 + nb * 64 + tid] = sh[tid];
    outp[48000 + 64000 + nb * 64 + tid] = creg;
  }
}

// ---------------- final projection: out = HS @ Wlin^T ----------------
// b128 compute reads: lane owns m-quad m=4*ks; 20 ds_read_b128/mt (was 80 b32).
#define KC4   40
#define HW_F  3072              // wtile float offset within a buffer
#define BUF_F 5120              // floats per buffer

__global__ void __launch_bounds__(256) k_gemm5(const float* __restrict__ hsg,
                                               const float* __restrict__ Wlin,
                                               float* __restrict__ part) {
  __shared__ float lds[2 * BUF_F];
  const int tid = threadIdx.x;
  const int kc = blockIdx.x % KC4;        // same kc -> same XCD (40 % 8 == 0)
  const int ng = blockIdx.x / KC4;
  const int nbase = ng * 32;
  const int kcbase = kc * 1600;           // 64000 / 40
  const int ks = tid & 15, nq = (tid >> 4) & 3, tq = tid >> 6;
  const int t0 = tq * 12, nb = nq * 8;
  const int m4 = ks * 4;                  // this lane's m-quad within the 64-m tile

  float acc[8][12];
#pragma unroll
  for (int j = 0; j < 8; ++j)
#pragma unroll
    for (int u = 0; u < 12; ++u) acc[j][u] = 0.f;

#define STAGE(dstbase, m0)                                                          \
  {                                                                                 \
    _Pragma("unroll")                                                               \
    for (int r = 0; r < 3; ++r) {                                                   \
      const int q = r * 256 + tid;                                                  \
      gld16(hsg + (q >> 4) * 64000 + (m0) + 4 * (q & 15), (dstbase) + 4 * q);       \
    }                                                                               \
    _Pragma("unroll")                                                               \
    for (int r = 0; r < 2; ++r) {                                                   \
      const int p = r * 256 + tid;                                                  \
      const int n_ = p >> 4, mr = p & 15;                                           \
      int ngl = nbase + n_; if (ngl > 999) ngl = 999;                               \
      gld16(Wlin + (size_t)ngl * 64000 + (m0) + 4 * mr, (dstbase) + HW_F + 4 * p);  \
    }                                                                               \
  }

  STAGE(lds, kcbase);
  __syncthreads();

  for (int mt = 0; mt < 25; ++mt) {
    const float* sbuf = lds + (mt & 1) * BUF_F;
    if (mt < 24) STAGE(lds + ((mt + 1) & 1) * BUF_F, kcbase + (mt + 1) * 64);
    float4 wv4[8];
#pragma unroll
    for (int j = 0; j < 8; ++j)
      wv4[j] = *(const float4*)(sbuf + HW_F + (nb + j) * 64 + m4);
#pragma unroll
    for (int u = 0; u < 12; ++u) {
      const float4 h4 = *(const float4*)(sbuf + (t0 + u) * 64 + m4);
#pragma unroll
      for (int j = 0; j < 8; ++j)
        acc[j][u] += wv4[j].x * h4.x + wv4[j].y * h4.y + wv4[j].z * h4.z + wv4[j].w * h4.w;
    }
    __syncthreads();   // drains vmcnt(0): next buffer complete; cur buffer free
  }
#undef STAGE

  // reduce the 16 k-slices (lanes differing in ks)
#pragma unroll
  for (int j = 0; j < 8; ++j)
#pragma unroll
    for (int u = 0; u < 12; ++u) {
      float v = acc[j][u];
      v += __shfl_xor(v, 8, 16);
      v += __shfl_xor(v, 4, 16);
      v += __shfl_xor(v, 2, 16);
      v += __shfl_xor(v, 1, 16);
      acc[j][u] = v;
    }
  if (ks == 0) {
#pragma unroll
    for (int j = 0; j < 8; ++j) {
      const int nglob = nbase + nb + j;
#pragma unroll
      for (int u = 0; u < 12; ++u)
        part[((kc * 48 + t0 + u) << 10) + nglob] = acc[j][u];
    }
  }
}

__global__ void k_reduce(const float* __restrict__ part, const float* __restrict__ blin,
                         float* __restrict__ outp) {
  const int id = blockIdx.x * 256 + threadIdx.x;
  if (id >= T_STEPS * N_NODES) return;
  const int t = id / N_NODES, n = id - t * N_NODES;
  float s = blin[n];
#pragma unroll
  for (int kc = 0; kc < KC4; ++kc) s += part[((kc * 48 + t) << 10) + n];
  outp[id] = s;
}

// ---------------- launch ----------------
extern "C" void kernel_launch(void* const* d_in, const int* in_sizes, int n_in,
                              void* d_out, int out_size, void* d_ws, size_t ws_size,
                              hipStream_t stream) {
  const float* x    = (const float*)d_in[0];
  const int*   ei   = (const int*)d_in[1];
  const float* h0   = (const float*)d_in[2];
  const float* c0   = (const float*)d_in[3];
  const float* Wg1  = (const float*)d_in[4];
  const float* bg1  = (const float*)d_in[5];
  const float* Wg2  = (const float*)d_in[6];
  const float* bg2  = (const float*)d_in[7];
  const float* Wih  = (const float*)d_in[8];
  const float* Whh  = (const float*)d_in[9];
  const float* bih  = (const float*)d_in[10];
  const float* bhh  = (const float*)d_in[11];
  const float* Wlin = (const float*)d_in[12];
  const float* blin = (const float*)d_in[13];
  float* outp = (float*)d_out;
  float* wsf  = (float*)d_ws;
  int*   wsi  = (int*)d_ws;

  int*   indeg  = wsi + O_INDEG;
  int*   fill   = wsi + O_FILL;
  int*   rowptr = wsi + O_ROWPTR;
  int*   csrc   = wsi + O_CSRC;
  float* cnorm  = wsf + O_CNORM;
  float* dinv   = wsf + O_DINV;
  float* selfn  = wsf + O_SELF;
  float* buf0   = wsf + O_BUF0;   // T1 -> T2 -> HS
  float* buf1   = wsf + O_BUF1;   // G1 -> G2 -> part

  k_zero<<<8, 256, 0, stream>>>(wsi);   // indeg[1000] + fill[1000]
  k_count<<<(E_EDGES + 255) / 256, 256, 0, stream>>>(ei, indeg);
  k_scan<<<1, 1024, 0, stream>>>(indeg, rowptr, dinv, selfn);
  k_scatter<<<(E_EDGES + 255) / 256, 256, 0, stream>>>(ei, rowptr, fill, dinv, csrc, cnorm);

  k_t1<<<750, 256, 0, stream>>>(x, Wg1, buf0);
  k_gath<<<1536, 256, 0, stream>>>(buf0, bg1, rowptr, csrc, cnorm, selfn, buf1, 1);  // G1
  k_mm2<<<750, 256, 0, stream>>>(buf1, Wg2, buf0);                                   // T2
  k_gath<<<1536, 256, 0, stream>>>(buf0, bg2, rowptr, csrc, cnorm, selfn, buf1, 0);  // G2
  k_lstm<<<1000, 256, 0, stream>>>(buf1, h0, c0, Wih, Whh, bih, bhh, buf0, outp);    // HS

  k_gemm5<<<KC4 * 32, 256, 0, stream>>>(buf0, Wlin, buf1);
  k_reduce<<<(T_STEPS * N_NODES + 255) / 256, 256, 0, stream>>>(buf1, blin, outp);
}

// Round 8
// 407.254 us; speedup vs baseline: 1.2030x; 1.2030x over previous
//
#include <hip/hip_runtime.h>
#include <math.h>

#define T_STEPS 48
#define N_NODES 1000
#define E_EDGES 32000
#define DIN     32
#define H_DIM   64

// ---- workspace layout (4-byte units) ----
#define O_INDEG  0         // int[1000]
#define O_FILL   1024      // int[1000]
#define O_ROWPTR 2048      // int[1001]
#define O_CSRC   4096      // int[32000]
#define O_CNORM  36864     // f32[32000]
#define O_DINV   69632     // f32[1000]
#define O_SELF   70656     // f32[1000]
#define O_BUF0   71680                    // f32[48*64000]  T1 -> T2 -> HS
#define O_BUF1   (71680 + 3072000)        // f32[48*64000]  G1 -> G2 -> part

__device__ __forceinline__ float sigmf(float v) { return 1.0f / (1.0f + __expf(-v)); }

// global -> LDS direct (16B per lane); dest must be wave-uniform base + lane*16
__device__ __forceinline__ void gld16(const void* g, void* l) {
  __builtin_amdgcn_global_load_lds((const __attribute__((address_space(1))) void*)g,
                                   (__attribute__((address_space(3))) void*)l, 16, 0, 0);
}

// ---------------- setup ----------------
__global__ void k_zero(int* __restrict__ p) { p[blockIdx.x * 256 + threadIdx.x] = 0; }

__global__ void k_count(const int* __restrict__ ei, int* __restrict__ indeg) {
  int e = blockIdx.x * 256 + threadIdx.x;
  if (e < E_EDGES) atomicAdd(&indeg[ei[E_EDGES + e]], 1);
}

__global__ void k_scan(const int* __restrict__ indeg, int* __restrict__ rowptr,
                       float* __restrict__ dinv, float* __restrict__ selfn) {
  __shared__ int sdat[1024];
  int tid = threadIdx.x;
  int v = (tid < N_NODES) ? indeg[tid] : 0;
  sdat[tid] = v;
  __syncthreads();
  for (int off = 1; off < 1024; off <<= 1) {
    int add = (tid >= off) ? sdat[tid - off] : 0;
    __syncthreads();
    sdat[tid] += add;
    __syncthreads();
  }
  if (tid < N_NODES) {
    rowptr[tid + 1] = sdat[tid];
    float di = rsqrtf((float)(v + 1));
    dinv[tid] = di;
    selfn[tid] = di * di;
  }
  if (tid == 0) rowptr[0] = 0;
}

__global__ void k_scatter(const int* __restrict__ ei, const int* __restrict__ rowptr,
                          int* __restrict__ fill, const float* __restrict__ dinv,
                          int* __restrict__ csrc, float* __restrict__ cnorm) {
  int e = blockIdx.x * 256 + threadIdx.x;
  if (e >= E_EDGES) return;
  int s = ei[e], d = ei[E_EDGES + e];
  int pos = atomicAdd(&fill[d], 1);
  int idx = rowptr[d] + pos;
  csrc[idx] = s;
  cnorm[idx] = dinv[s] * dinv[d];
}

// ---------------- T1 = x @ Wg1 ----------------
__global__ void __launch_bounds__(256) k_t1(const float* __restrict__ x,
                                            const float* __restrict__ Wg1,
                                            float* __restrict__ T1) {
  __shared__ float sWT[H_DIM * 36];     // transposed: sWT[h][k]
  __shared__ float sx[4][DIN];
  const int tid = threadIdx.x, wv = tid >> 6, h = tid & 63;
  for (int i = tid; i < DIN * H_DIM; i += 256) sWT[(i & 63) * 36 + (i >> 6)] = Wg1[i];
  __syncthreads();
  const int r0 = blockIdx.x * 64 + wv * 16;
  const float4* wrow = (const float4*)&sWT[h * 36];
  for (int it = 0; it < 16; ++it) {
    const int r = r0 + it;
    if (h < DIN) sx[wv][h] = x[r * DIN + h];   // wave-local
    float acc = 0.f;
    const float4* xp = (const float4*)&sx[wv][0];
#pragma unroll
    for (int k4 = 0; k4 < 8; ++k4) {
      float4 xv = xp[k4], wv4 = wrow[k4];
      acc += xv.x * wv4.x + xv.y * wv4.y + xv.z * wv4.z + xv.w * wv4.w;
    }
    T1[r * H_DIM + h] = acc;
  }
}

// ---------------- gather: dst = gather(Tsrc)+self+bias, optional relu ----------------
// 8-deep rotating prefetch: batch k+1's loads issue while batch k's FMAs run.
__device__ __forceinline__ float gath_node(const float* __restrict__ Tsrc,
                                           const int* __restrict__ es,
                                           const float* __restrict__ ew,
                                           int cnt, int h) {
  float a0 = 0.f, a1 = 0.f, a2 = 0.f, a3 = 0.f;
  float a4 = 0.f, a5 = 0.f, a6 = 0.f, a7 = 0.f;
  int e = 0;
  if (cnt >= 8) {
    float p0 = Tsrc[es[0] * 64 + h], p1 = Tsrc[es[1] * 64 + h];
    float p2 = Tsrc[es[2] * 64 + h], p3 = Tsrc[es[3] * 64 + h];
    float p4 = Tsrc[es[4] * 64 + h], p5 = Tsrc[es[5] * 64 + h];
    float p6 = Tsrc[es[6] * 64 + h], p7 = Tsrc[es[7] * 64 + h];
    for (e = 8; e + 8 <= cnt; e += 8) {
      float n0 = Tsrc[es[e + 0] * 64 + h], n1 = Tsrc[es[e + 1] * 64 + h];
      float n2 = Tsrc[es[e + 2] * 64 + h], n3 = Tsrc[es[e + 3] * 64 + h];
      float n4 = Tsrc[es[e + 4] * 64 + h], n5 = Tsrc[es[e + 5] * 64 + h];
      float n6 = Tsrc[es[e + 6] * 64 + h], n7 = Tsrc[es[e + 7] * 64 + h];
      a0 += ew[e - 8] * p0; a1 += ew[e - 7] * p1;
      a2 += ew[e - 6] * p2; a3 += ew[e - 5] * p3;
      a4 += ew[e - 4] * p4; a5 += ew[e - 3] * p5;
      a6 += ew[e - 2] * p6; a7 += ew[e - 1] * p7;
      p0 = n0; p1 = n1; p2 = n2; p3 = n3; p4 = n4; p5 = n5; p6 = n6; p7 = n7;
    }
    a0 += ew[e - 8] * p0; a1 += ew[e - 7] * p1;
    a2 += ew[e - 6] * p2; a3 += ew[e - 5] * p3;
    a4 += ew[e - 4] * p4; a5 += ew[e - 3] * p5;
    a6 += ew[e - 2] * p6; a7 += ew[e - 1] * p7;
  }
  for (; e < cnt; ++e) a0 += ew[e] * Tsrc[es[e] * 64 + h];
  return ((a0 + a1) + (a2 + a3)) + ((a4 + a5) + (a6 + a7));
}

// 32 nodes / block -> 1536 blocks (6/CU) for latency-hiding TLP
#define ECHUNK 1536
__global__ void __launch_bounds__(256) k_gath(const float* __restrict__ Tall,
                                              const float* __restrict__ bias,
                                              const int* __restrict__ rowptr,
                                              const int* __restrict__ csrc,
                                              const float* __restrict__ cnorm,
                                              const float* __restrict__ selfn,
                                              float* __restrict__ Dall, int relu) {
  __shared__ int   s_src[ECHUNK];
  __shared__ float s_wt[ECHUNK];
  __shared__ float sb[64];
  const int tid = threadIdx.x, wv = tid >> 6, h = tid & 63;
  if (tid < 64) sb[tid] = bias[tid];
  const int t = blockIdx.x >> 5, nb32 = (blockIdx.x & 31) * 32;
  const float* Tsrc = Tall + t * 64000;
  float* dst = Dall + t * 64000;
  const int nE = (nb32 + 32 < N_NODES) ? nb32 + 32 : N_NODES;
  const int r0 = rowptr[nb32], r1 = rowptr[nE];
  const int tot = r1 - r0;
  const bool fits = (tot <= ECHUNK);
  if (fits)
    for (int i = tid; i < tot; i += 256) { s_src[i] = csrc[r0 + i]; s_wt[i] = cnorm[r0 + i]; }
  __syncthreads();
  for (int i = 0; i < 8; ++i) {
    const int n = nb32 + wv * 8 + i;
    if (n >= N_NODES) continue;
    const int a = rowptr[n], b = rowptr[n + 1];
    float acc = selfn[n] * Tsrc[n * 64 + h];
    if (fits) {
      acc += gath_node(Tsrc, s_src + (a - r0), s_wt + (a - r0), b - a, h);
    } else {
      for (int e = a; e < b; ++e) acc += cnorm[e] * Tsrc[csrc[e] * 64 + h];
    }
    acc += sb[h];
    if (relu) acc = fmaxf(acc, 0.f);
    dst[n * 64 + h] = acc;
  }
}

// ---------------- T2 = G1 @ Wg2 (48000 x 64 x 64) ----------------
__global__ void __launch_bounds__(256) k_mm2(const float* __restrict__ G1,
                                             const float* __restrict__ Wg2,
                                             float* __restrict__ T2) {
  __shared__ float sW[H_DIM * H_DIM];   // [k][h] broadcast form, conflict-free
  __shared__ float sx[4][H_DIM];
  const int tid = threadIdx.x, wv = tid >> 6, h = tid & 63;
  for (int i = tid; i < H_DIM * H_DIM; i += 256) sW[i] = Wg2[i];
  __syncthreads();
  const int r0 = blockIdx.x * 64 + wv * 16;
  for (int it = 0; it < 16; ++it) {
    const int r = r0 + it;
    sx[wv][h] = G1[r * 64 + h];   // wave-local write then read
    float acc = 0.f;
#pragma unroll
    for (int k = 0; k < H_DIM; ++k) acc += sx[wv][k] * sW[k * H_DIM + h];
    T2[r * 64 + h] = acc;
  }
}

// ---------------- LSTM scan: 1 node / block ----------------
__global__ void __launch_bounds__(256) k_lstm(const float* __restrict__ G2,
                                              const float* __restrict__ h0,
                                              const float* __restrict__ c0,
                                              const float* __restrict__ Wih,
                                              const float* __restrict__ Whh,
                                              const float* __restrict__ bih,
                                              const float* __restrict__ bhh,
                                              float* __restrict__ hsg,
                                              float* __restrict__ outp) {
  const int tid = threadIdx.x, nb = blockIdx.x;
  __shared__ float sh[64];
  __shared__ float sg2[2][64];
  __shared__ float sgates[256];
  float4 Wih4[16], Whh4[16];
  {
    const float4* wp = (const float4*)(Wih + tid * H_DIM);
    const float4* vp = (const float4*)(Whh + tid * H_DIM);
#pragma unroll
    for (int k = 0; k < 16; ++k) { Wih4[k] = wp[k]; Whh4[k] = vp[k]; }
  }
  const float bsum = bih[tid] + bhh[tid];
  float creg = 0.f;
  if (tid < 64) {
    sh[tid] = h0[nb * 64 + tid];
    creg = c0[nb * 64 + tid];
    sg2[0][tid] = G2[nb * 64 + tid];
  }
  __syncthreads();
  for (int t = 0; t < T_STEPS; ++t) {
    const int cur = t & 1;
    float gnext = 0.f;
    if (t < T_STEPS - 1 && tid < 64) gnext = G2[(t + 1) * 64000 + nb * 64 + tid];
    float gv = bsum;
    const float4* gp = (const float4*)&sg2[cur][0];
    const float4* hp = (const float4*)sh;
#pragma unroll
    for (int k = 0; k < 16; ++k) {
      float4 a = gp[k], b = hp[k];
      gv += a.x * Wih4[k].x + a.y * Wih4[k].y + a.z * Wih4[k].z + a.w * Wih4[k].w;
      gv += b.x * Whh4[k].x + b.y * Whh4[k].y + b.z * Whh4[k].z + b.w * Whh4[k].w;
    }
    sgates[tid] = gv;
    __syncthreads();
    if (tid < 64) {
      float iv = sgates[tid], fv = sgates[64 + tid], gg = sgates[128 + tid], ov = sgates[192 + tid];
      float cn = sigmf(fv) * creg + sigmf(iv) * tanhf(gg);
      float hn = sigmf(ov) * tanhf(cn);
      creg = cn;
      sh[tid] = hn;
      hsg[t * 64000 + nb * 64 + tid] = hn;
      if (t < T_STEPS - 1) sg2[cur ^ 1][tid] = gnext;
    }
    __syncthreads();
  }
  if (tid < 64) {
    outp[48000 + nb * 64 + tid] = sh[tid];
    outp[48000 + 64000 + nb * 64 + tid] = creg;
  }
}

// ---------------- final projection: out = HS @ Wlin^T ----------------
// W streamed global->reg (rotating prefetch, no LDS, no W barrier cost);
// HS LDS double-buffered via global_load_lds, broadcast b128 reads.
// grid 2560 = kc40 x ng64; per block: 16 n x 48 t x 1600 m.
#define KC4   40
#define HSB_F 3072              // floats per HS buffer ([48][64])

__global__ void __launch_bounds__(256, 4) k_gemm6(const float* __restrict__ hsg,
                                                  const float* __restrict__ Wlin,
                                                  float* __restrict__ part) {
  __shared__ float lds[2 * HSB_F];
  const int tid = threadIdx.x;
  const int kc = blockIdx.x % KC4;        // same kc -> same XCD (40 % 8 == 0)
  const int ng = blockIdx.x / KC4;        // 0..63
  const int nbase = ng * 16;
  const int kcbase = kc * 1600;           // 64000 / 40
  const int ks = tid & 15, nq = (tid >> 4) & 3, tq = tid >> 6;
  const int t0 = tq * 12;
  const int m4 = ks * 4;                  // this lane's m-quad within the 64-m tile

  // W row base pointers for this lane's 4 output nodes (clamped; dup rows are
  // computed but never written for nglob > 999)
  const float* wrow[4];
#pragma unroll
  for (int j = 0; j < 4; ++j) {
    int ngl = nbase + nq * 4 + j;
    if (ngl > N_NODES - 1) ngl = N_NODES - 1;
    wrow[j] = Wlin + (size_t)ngl * 64000 + kcbase + m4;
  }

  float acc[4][12];
#pragma unroll
  for (int j = 0; j < 4; ++j)
#pragma unroll
    for (int u = 0; u < 12; ++u) acc[j][u] = 0.f;

  // HS staging: 768 f4 per buffer = 3 full-wave rounds, linear [t][m] layout
#define STAGE6(dstbase, m0)                                                   \
  {                                                                           \
    _Pragma("unroll")                                                         \
    for (int r = 0; r < 3; ++r) {                                             \
      const int q = r * 256 + tid;                                            \
      gld16(hsg + (q >> 4) * 64000 + (m0) + 4 * (q & 15), (dstbase) + 4 * q); \
    }                                                                         \
  }

  STAGE6(lds, kcbase);
  float4 Wc[4], Wn[4];
#pragma unroll
  for (int j = 0; j < 4; ++j) {
    Wc[j] = *(const float4*)(wrow[j]);
    Wn[j] = make_float4(0.f, 0.f, 0.f, 0.f);
  }
  __syncthreads();

  for (int mt = 0; mt < 25; ++mt) {
    const float* sbuf = lds + (mt & 1) * HSB_F;
    if (mt < 24) {
      STAGE6(lds + ((mt + 1) & 1) * HSB_F, kcbase + (mt + 1) * 64);
#pragma unroll
      for (int j = 0; j < 4; ++j) Wn[j] = *(const float4*)(wrow[j] + (mt + 1) * 64);
    }
#pragma unroll
    for (int u = 0; u < 12; ++u) {
      const float4 h4 = *(const float4*)(sbuf + (t0 + u) * 64 + m4);
#pragma unroll
      for (int j = 0; j < 4; ++j)
        acc[j][u] += Wc[j].x * h4.x + Wc[j].y * h4.y + Wc[j].z * h4.z + Wc[j].w * h4.w;
    }
    __syncthreads();   // next HS buffer landed (vmcnt(0) drain); cur buffer free
#pragma unroll
    for (int j = 0; j < 4; ++j) Wc[j] = Wn[j];
  }
#undef STAGE6

  // reduce the 16 k-slices (lanes differing in ks)
#pragma unroll
  for (int j = 0; j < 4; ++j)
#pragma unroll
    for (int u = 0; u < 12; ++u) {
      float v = acc[j][u];
      v += __shfl_xor(v, 8, 16);
      v += __shfl_xor(v, 4, 16);
      v += __shfl_xor(v, 2, 16);
      v += __shfl_xor(v, 1, 16);
      acc[j][u] = v;
    }
  if (ks == 0) {
#pragma unroll
    for (int j = 0; j < 4; ++j) {
      const int nglob = nbase + nq * 4 + j;
      if (nglob < N_NODES) {
#pragma unroll
        for (int u = 0; u < 12; ++u)
          part[((kc * 48 + t0 + u) << 10) + nglob] = acc[j][u];
      }
    }
  }
}

__global__ void k_reduce(const float* __restrict__ part, const float* __restrict__ blin,
                         float* __restrict__ outp) {
  const int id = blockIdx.x * 256 + threadIdx.x;
  if (id >= T_STEPS * N_NODES) return;
  const int t = id / N_NODES, n = id - t * N_NODES;
  float s = blin[n];
#pragma unroll
  for (int kc = 0; kc < KC4; ++kc) s += part[((kc * 48 + t) << 10) + n];
  outp[id] = s;
}

// ---------------- launch ----------------
extern "C" void kernel_launch(void* const* d_in, const int* in_sizes, int n_in,
                              void* d_out, int out_size, void* d_ws, size_t ws_size,
                              hipStream_t stream) {
  const float* x    = (const float*)d_in[0];
  const int*   ei   = (const int*)d_in[1];
  const float* h0   = (const float*)d_in[2];
  const float* c0   = (const float*)d_in[3];
  const float* Wg1  = (const float*)d_in[4];
  const float* bg1  = (const float*)d_in[5];
  const float* Wg2  = (const float*)d_in[6];
  const float* bg2  = (const float*)d_in[7];
  const float* Wih  = (const float*)d_in[8];
  const float* Whh  = (const float*)d_in[9];
  const float* bih  = (const float*)d_in[10];
  const float* bhh  = (const float*)d_in[11];
  const float* Wlin = (const float*)d_in[12];
  const float* blin = (const float*)d_in[13];
  float* outp = (float*)d_out;
  float* wsf  = (float*)d_ws;
  int*   wsi  = (int*)d_ws;

  int*   indeg  = wsi + O_INDEG;
  int*   fill   = wsi + O_FILL;
  int*   rowptr = wsi + O_ROWPTR;
  int*   csrc   = wsi + O_CSRC;
  float* cnorm  = wsf + O_CNORM;
  float* dinv   = wsf + O_DINV;
  float* selfn  = wsf + O_SELF;
  float* buf0   = wsf + O_BUF0;   // T1 -> T2 -> HS
  float* buf1   = wsf + O_BUF1;   // G1 -> G2 -> part

  k_zero<<<8, 256, 0, stream>>>(wsi);   // indeg[1000] + fill[1000]
  k_count<<<(E_EDGES + 255) / 256, 256, 0, stream>>>(ei, indeg);
  k_scan<<<1, 1024, 0, stream>>>(indeg, rowptr, dinv, selfn);
  k_scatter<<<(E_EDGES + 255) / 256, 256, 0, stream>>>(ei, rowptr, fill, dinv, csrc, cnorm);

  k_t1<<<750, 256, 0, stream>>>(x, Wg1, buf0);
  k_gath<<<1536, 256, 0, stream>>>(buf0, bg1, rowptr, csrc, cnorm, selfn, buf1, 1);  // G1
  k_mm2<<<750, 256, 0, stream>>>(buf1, Wg2, buf0);                                   // T2
  k_gath<<<1536, 256, 0, stream>>>(buf0, bg2, rowptr, csrc, cnorm, selfn, buf1, 0);  // G2
  k_lstm<<<1000, 256, 0, stream>>>(buf1, h0, c0, Wih, Whh, bih, bhh, buf0, outp);    // HS

  k_gemm6<<<KC4 * 64, 256, 0, stream>>>(buf0, Wlin, buf1);
  k_reduce<<<(T_STEPS * N_NODES + 255) / 256, 256, 0, stream>>>(buf1, blin, outp);
}